// Round 13
// baseline (389.780 us; speedup 1.0000x reference)
//
#include <hip/hip_runtime.h>
#include <hip/hip_bf16.h>
#include <stdint.h>

#define N_NODES 50000
#define N_EDGES 800000
#define IN_FEAT 256
#define OUT_FEAT 256
#define NUM_RELS 64
#define NUM_BASES 8
#define KTOT 2304           // logical K: 8*256 (bases) + 256 (self loop)
#define MP 50176            // 1568 * 32 padded M
#define SCAN_BLKS 196
#define ROWB 4608           // LDS row stride bytes (2304 bf16 = 288 chunks of 16B)

typedef __attribute__((ext_vector_type(8))) __bf16 bf16x8;
typedef __attribute__((ext_vector_type(4))) __bf16 bf16x4;
typedef __attribute__((ext_vector_type(4))) float f32x4;
typedef __attribute__((ext_vector_type(2))) float f32x2;

// ---------------- x -> bf16 ----------------
__global__ void k_prex(const float* __restrict__ x, __bf16* __restrict__ xb) {
  int i = blockIdx.x * 256 + threadIdx.x;
  const float4* xp = (const float4*)x;
  float4 u = xp[i * 2], v = xp[i * 2 + 1];
  bf16x8 o;
  o[0] = (__bf16)u.x; o[1] = (__bf16)u.y; o[2] = (__bf16)u.z; o[3] = (__bf16)u.w;
  o[4] = (__bf16)v.x; o[5] = (__bf16)v.y; o[6] = (__bf16)v.z; o[7] = (__bf16)v.w;
  *(bf16x8*)(xb + (size_t)i * 8) = o;
}

// ---------------- CSR build ----------------
__global__ void k_count(const int* __restrict__ dst, int* __restrict__ deg) {
  int e = blockIdx.x * 256 + threadIdx.x;
  atomicAdd(&deg[dst[e]], 1);
}

__global__ void k_scan1(const int* __restrict__ deg, int* __restrict__ offs,
                        int* __restrict__ bsum) {
  __shared__ int s[256];
  int t = threadIdx.x;
  int i = blockIdx.x * 256 + t;
  int v = (i < N_NODES) ? deg[i] : 0;
  s[t] = v;
  __syncthreads();
  for (int d = 1; d < 256; d <<= 1) {
    int y = (t >= d) ? s[t - d] : 0;
    __syncthreads();
    s[t] += y;
    __syncthreads();
  }
  if (i < N_NODES) offs[i] = s[t] - v;
  if (t == 255) bsum[blockIdx.x] = s[255];
}

__global__ void k_scan3(int* __restrict__ offs, const int* __restrict__ bsum,
                        int* __restrict__ fill) {
  __shared__ int s[256];
  int t = threadIdx.x;
  s[t] = (t < SCAN_BLKS && t < blockIdx.x) ? bsum[t] : 0;
  __syncthreads();
  for (int d = 128; d; d >>= 1) {
    if (t < d) s[t] += s[t + d];
    __syncthreads();
  }
  int base = s[0];
  int i = blockIdx.x * 256 + t;
  if (i < N_NODES) {
    int o = offs[i] + base;
    offs[i] = o;
    fill[i] = o;
  }
}

__global__ void k_scatter(const int* __restrict__ dst, const int* __restrict__ srcv,
                          const int* __restrict__ ety, const float* __restrict__ norm,
                          int* __restrict__ fill, uint2* __restrict__ erec) {
  int e = blockIdx.x * 256 + threadIdx.x;
  int pos = atomicAdd(&fill[dst[e]], 1);
  erec[pos] = make_uint2((unsigned)srcv[e] | ((unsigned)ety[e] << 16),
                         __float_as_uint(norm[e]));
}

// -------- W -> MFMA-fragment order: Wf[F*64 + lane] (16B), F = kt*16 + nf ---
__global__ void k_prepwf(const float* __restrict__ weight, const float* __restrict__ loop_w,
                         __bf16* __restrict__ Wf) {
  int tid = blockIdx.x * 256 + threadIdx.x;   // grid 288 -> 73728
  int lane6 = tid & 63;
  int F = tid >> 6;
  int kt2 = F >> 4;
  int nf = F & 15;
  int o = nf * 16 + (lane6 & 15);
  int rbase = kt2 * 32 + (lane6 >> 4) * 8;
  bf16x8 v;
#pragma unroll
  for (int j = 0; j < 8; ++j) {
    int r = rbase + j;
    float f = (r < 2048) ? weight[(size_t)r * 256 + o]
                         : loop_w[(size_t)(r - 2048) * 256 + o];
    v[j] = (__bf16)f;
  }
  *(bf16x8*)(Wf + (size_t)tid * 8) = v;
}

// ---- per-edge FMA body (round-11 proven): et -> SGPR, coef via s_load ------
#define AGGE(R, XV, ACC)                                                      \
  do {                                                                        \
    int et_ = __builtin_amdgcn_readfirstlane((int)((R).x >> 16));             \
    float nm_ = __uint_as_float((R).y);                                       \
    f32x2 v0_ = {__uint_as_float((XV).x << 16) * nm_,                         \
                 __uint_as_float((XV).x & 0xffff0000u) * nm_};                 \
    f32x2 v1_ = {__uint_as_float((XV).y << 16) * nm_,                         \
                 __uint_as_float((XV).y & 0xffff0000u) * nm_};                 \
    f32x4 cl_ = *(const f32x4*)(w_comp + et_ * 8);                            \
    f32x4 ch_ = *(const f32x4*)(w_comp + et_ * 8 + 4);                        \
    _Pragma("unroll") for (int b = 0; b < 4; ++b) {                           \
      ACC[b][0] += v0_ * cl_[b];                                              \
      ACC[b][1] += v1_ * cl_[b];                                              \
      ACC[b + 4][0] += v0_ * ch_[b];                                          \
      ACC[b + 4][1] += v1_ * ch_[b];                                          \
    }                                                                         \
  } while (0)

#define EDGE4(RP, I, ACC)                                                     \
  do {                                                                        \
    uint2 r0_ = (RP)[(I) + 0], r1_ = (RP)[(I) + 1];                           \
    uint2 r2_ = (RP)[(I) + 2], r3_ = (RP)[(I) + 3];                           \
    uint2 x0_ = *(const uint2*)(xb + (size_t)(r0_.x & 0xffffu) * IN_FEAT + lo4);\
    uint2 x1_ = *(const uint2*)(xb + (size_t)(r1_.x & 0xffffu) * IN_FEAT + lo4);\
    uint2 x2_ = *(const uint2*)(xb + (size_t)(r2_.x & 0xffffu) * IN_FEAT + lo4);\
    uint2 x3_ = *(const uint2*)(xb + (size_t)(r3_.x & 0xffffu) * IN_FEAT + lo4);\
    AGGE(r0_, x0_, ACC); AGGE(r1_, x1_, ACC);                                 \
    AGGE(r2_, x2_, ACC); AGGE(r3_, x3_, ACC);                                 \
  } while (0)

#define EDGE1(RP, I, ACC)                                                     \
  do {                                                                        \
    uint2 r_ = (RP)[(I)];                                                     \
    uint2 x_ = *(const uint2*)(xb + (size_t)(r_.x & 0xffffu) * IN_FEAT + lo4);\
    AGGE(r_, x_, ACC);                                                        \
  } while (0)

// write one node's 2048 agg values + 256 self-loop values into swizzled LDS.
// logical 16B-chunk c of row R -> phys c ^ (R&7); lane owns 8B halves.
#define WRITE_ROW(ACC, R, NODE)                                               \
  do {                                                                        \
    char* rowp_ = sA + (size_t)(R) * ROWB;                                    \
    _Pragma("unroll") for (int b = 0; b < 8; ++b) {                           \
      int cp_ = (b * 32 + (lane >> 1)) ^ ((R) & 7);                           \
      bf16x4 o_;                                                              \
      o_[0] = (__bf16)ACC[b][0][0]; o_[1] = (__bf16)ACC[b][0][1];             \
      o_[2] = (__bf16)ACC[b][1][0]; o_[3] = (__bf16)ACC[b][1][1];             \
      *(bf16x4*)(rowp_ + cp_ * 16 + (lane & 1) * 8) = o_;                     \
    }                                                                         \
    uint2 xv_ = ((NODE) < N_NODES)                                            \
        ? *(const uint2*)(xb + (size_t)(NODE) * IN_FEAT + lo4)                \
        : make_uint2(0u, 0u);                                                 \
    int cx_ = (256 + (lane >> 1)) ^ ((R) & 7);                                \
    *(uint2*)(rowp_ + cx_ * 16 + (lane & 1) * 8) = xv_;                       \
  } while (0)

// dual-chain aggregation of two nodes (round-11 loop), result -> LDS
#define AGG_PAIR(NA, NB, RA, RB)                                              \
  do {                                                                        \
    f32x2 acca[8][2], accb[8][2];                                             \
    _Pragma("unroll") for (int b = 0; b < 8; ++b) {                           \
      acca[b][0] = f32x2{0.f, 0.f}; acca[b][1] = f32x2{0.f, 0.f};             \
      accb[b][0] = f32x2{0.f, 0.f}; accb[b][1] = f32x2{0.f, 0.f};             \
    }                                                                         \
    int i0a = 0, ca = 0, i0b = 0, cb = 0;                                     \
    if ((NA) < N_NODES) {                                                     \
      i0a = __builtin_amdgcn_readfirstlane(offs[NA]);                         \
      ca  = __builtin_amdgcn_readfirstlane(fin[NA]) - i0a;                    \
    }                                                                         \
    if ((NB) < N_NODES) {                                                     \
      i0b = __builtin_amdgcn_readfirstlane(offs[NB]);                         \
      cb  = __builtin_amdgcn_readfirstlane(fin[NB]) - i0b;                    \
    }                                                                         \
    const uint2* rpa = erec + i0a;                                            \
    const uint2* rpb = erec + i0b;                                            \
    int ia = 0, ib = 0;                                                       \
    int mm = (ca < cb ? ca : cb) & ~3;                                        \
    for (; ia < mm; ia += 4, ib += 4) {                                       \
      EDGE4(rpa, ia, acca);                                                   \
      EDGE4(rpb, ib, accb);                                                   \
    }                                                                         \
    for (; ia + 4 <= ca; ia += 4) EDGE4(rpa, ia, acca);                       \
    for (; ib + 4 <= cb; ib += 4) EDGE4(rpb, ib, accb);                       \
    for (; ia < ca; ++ia) EDGE1(rpa, ia, acca);                               \
    for (; ib < cb; ++ib) EDGE1(rpb, ib, accb);                               \
    WRITE_ROW(acca, RA, NA);                                                  \
    WRITE_ROW(accb, RB, NB);                                                  \
  } while (0)

// ---------------- FUSED: aggregate 32 nodes -> LDS -> GEMM -> out -----------
// 8 waves. Phase 1: wave w aggregates nodes [tm*32+4w, +4) into LDS rows.
// ONE barrier. Phase 2: barrier-free GEMM [32][2304] @ Wcat: per wave
// 2 m-frags x 2 n-frags (cols w*32..+31), A via ds_read_b128 (read-only LDS),
// B from frag-packed Wf (L2), double-buffered. No staging convoy.
__global__ __launch_bounds__(512, 1) void k_fused(
    const __bf16* __restrict__ xb, const float* __restrict__ w_comp,
    const int* __restrict__ offs, const int* __restrict__ fin,
    const uint2* __restrict__ erec, const __bf16* __restrict__ Wf,
    const float* __restrict__ bias, float* __restrict__ out) {
  __shared__ __align__(16) char sA[32 * ROWB];   // 144KB

  int t = threadIdx.x;
  int wid = t >> 6, lane = t & 63;
  int tm = blockIdx.x;
  int lo4 = lane * 4;

  {
    int nb0 = tm * 32 + wid * 4;
    AGG_PAIR(nb0,     nb0 + 1, wid * 4,     wid * 4 + 1);
    AGG_PAIR(nb0 + 2, nb0 + 3, wid * 4 + 2, wid * 4 + 3);
  }
  __syncthreads();

  // ---- phase 2 ----
  int frow = lane & 15, g = lane >> 4;
  int xsw = frow & 7;                       // (mf*16+frow)&7 == frow&7
  const char* ap[2] = { (const char*)sA + (size_t)frow * ROWB,
                        (const char*)sA + (size_t)(16 + frow) * ROWB };
  const __bf16* wfb = Wf + (size_t)(wid * 2) * 512 + lane * 8;

  f32x4 acc2[2][2];
#pragma unroll
  for (int m = 0; m < 2; ++m)
#pragma unroll
    for (int n = 0; n < 2; ++n) acc2[m][n] = f32x4{0.f, 0.f, 0.f, 0.f};

  bf16x8 Ac[2], B0[2], B1[2];

#define LD_A(KT, D)                                                           \
  do {                                                                        \
    _Pragma("unroll") for (int mf = 0; mf < 2; ++mf)                          \
        D[mf] = *(const bf16x8*)(ap[mf] + ((((KT) * 4 + g) ^ xsw) * 16));     \
  } while (0)

#define LD_B(KT, D)                                                           \
  do {                                                                        \
    _Pragma("unroll") for (int nf = 0; nf < 2; ++nf)                          \
        D[nf] = *(const bf16x8*)(wfb + (size_t)((KT) * 16 + nf) * 512);       \
  } while (0)

#define FMA4(BS)                                                              \
  do {                                                                        \
    _Pragma("unroll") for (int mf = 0; mf < 2; ++mf)                          \
    _Pragma("unroll") for (int nf = 0; nf < 2; ++nf)                          \
        acc2[mf][nf] = __builtin_amdgcn_mfma_f32_16x16x32_bf16(               \
            Ac[mf], BS[nf], acc2[mf][nf], 0, 0, 0);                           \
  } while (0)

  LD_B(0, B0);
  for (int kt = 0; kt < 72; kt += 2) {
    int n1 = kt + 1;
    int n2 = (kt + 2 < 72) ? kt + 2 : 71;
    LD_A(kt, Ac); LD_B(n1, B1); FMA4(B0);
    LD_A(n1, Ac); LD_B(n2, B0); FMA4(B1);
  }
#undef LD_A
#undef LD_B
#undef FMA4

  // epilogue: C/D layout col = lane&15, row = (lane>>4)*4 + j
  int r0 = (lane >> 4) * 4;
  int c0 = lane & 15;
#pragma unroll
  for (int mf = 0; mf < 2; ++mf) {
    int rowb = tm * 32 + mf * 16 + r0;
#pragma unroll
    for (int nf = 0; nf < 2; ++nf) {
      int col = (wid * 2 + nf) * 16 + c0;
      float bv = bias[col];
#pragma unroll
      for (int j = 0; j < 4; ++j) {
        int row = rowb + j;
        if (row < N_NODES) {
          float v = acc2[mf][nf][j] + bv;
          out[(size_t)row * OUT_FEAT + col] = v > 0.f ? v : 0.f;
        }
      }
    }
  }
}

extern "C" void kernel_launch(void* const* d_in, const int* in_sizes, int n_in,
                              void* d_out, int out_size, void* d_ws, size_t ws_size,
                              hipStream_t stream) {
  const float* x      = (const float*)d_in[0];
  const int*   src    = (const int*)d_in[1];
  const int*   dst    = (const int*)d_in[2];
  const int*   ety    = (const int*)d_in[3];
  const float* norm   = (const float*)d_in[4];
  const float* weight = (const float*)d_in[5];
  const float* w_comp = (const float*)d_in[6];
  const float* h_bias = (const float*)d_in[7];
  const float* loop_w = (const float*)d_in[8];
  float* out = (float*)d_out;

  char* ws = (char*)d_ws;
  __bf16* xb = (__bf16*)ws;                                 // 25.7MB
  size_t off = (size_t)MP * IN_FEAT * 2;
  __bf16* Wf = (__bf16*)(ws + off);                         // 1.18MB (frag-packed W)
  off += (size_t)256 * KTOT * 2;
  uint2* erec = (uint2*)(ws + off);                         // 6.4MB
  off += (size_t)N_EDGES * 8;
  int* deg   = (int*)(ws + off);
  int* offs  = deg + N_NODES;
  int* fill  = offs + N_NODES;
  int* bsum  = fill + N_NODES;

  hipMemsetAsync(deg, 0, N_NODES * sizeof(int), stream);
  k_prex<<<(N_NODES * IN_FEAT / 8) / 256, 256, 0, stream>>>(x, xb);
  k_count<<<N_EDGES / 256, 256, 0, stream>>>(dst, deg);
  k_scan1<<<SCAN_BLKS, 256, 0, stream>>>(deg, offs, bsum);
  k_scan3<<<SCAN_BLKS, 256, 0, stream>>>(offs, bsum, fill);
  k_scatter<<<N_EDGES / 256, 256, 0, stream>>>(dst, src, ety, norm, fill, erec);
  k_prepwf<<<288, 256, 0, stream>>>(weight, loop_w, Wf);
  k_fused<<<MP / 32, 512, 0, stream>>>(xb, w_comp, offs, fill, erec, Wf, h_bias, out);
}

// Round 14
// 297.840 us; speedup vs baseline: 1.3087x; 1.3087x over previous
//
#include <hip/hip_runtime.h>
#include <hip/hip_bf16.h>
#include <stdint.h>

#define N_NODES 50000
#define N_EDGES 800000
#define IN_FEAT 256
#define OUT_FEAT 256
#define NUM_RELS 64
#define NUM_BASES 8
#define KTOT 2304           // logical K: 8*256 (bases) + 256 (self loop)
#define MP 50176            // 1568 * 32 padded M
#define SCAN_BLKS 196
#define ROWB 4624           // LDS row stride bytes: 289 chunks (odd) -> no bank align

typedef __attribute__((ext_vector_type(8))) __bf16 bf16x8;
typedef __attribute__((ext_vector_type(4))) __bf16 bf16x4;
typedef __attribute__((ext_vector_type(4))) float f32x4;
typedef __attribute__((ext_vector_type(2))) float f32x2;

// ---------------- x -> bf16 ----------------
__global__ void k_prex(const float* __restrict__ x, __bf16* __restrict__ xb) {
  int i = blockIdx.x * 256 + threadIdx.x;
  const float4* xp = (const float4*)x;
  float4 u = xp[i * 2], v = xp[i * 2 + 1];
  bf16x8 o;
  o[0] = (__bf16)u.x; o[1] = (__bf16)u.y; o[2] = (__bf16)u.z; o[3] = (__bf16)u.w;
  o[4] = (__bf16)v.x; o[5] = (__bf16)v.y; o[6] = (__bf16)v.z; o[7] = (__bf16)v.w;
  *(bf16x8*)(xb + (size_t)i * 8) = o;
}

// ---------------- CSR build ----------------
__global__ void k_count(const int* __restrict__ dst, int* __restrict__ deg) {
  int e = blockIdx.x * 256 + threadIdx.x;
  atomicAdd(&deg[dst[e]], 1);
}

__global__ void k_scan1(const int* __restrict__ deg, int* __restrict__ offs,
                        int* __restrict__ bsum) {
  __shared__ int s[256];
  int t = threadIdx.x;
  int i = blockIdx.x * 256 + t;
  int v = (i < N_NODES) ? deg[i] : 0;
  s[t] = v;
  __syncthreads();
  for (int d = 1; d < 256; d <<= 1) {
    int y = (t >= d) ? s[t - d] : 0;
    __syncthreads();
    s[t] += y;
    __syncthreads();
  }
  if (i < N_NODES) offs[i] = s[t] - v;
  if (t == 255) bsum[blockIdx.x] = s[255];
}

__global__ void k_scan3(int* __restrict__ offs, const int* __restrict__ bsum,
                        int* __restrict__ fill) {
  __shared__ int s[256];
  int t = threadIdx.x;
  s[t] = (t < SCAN_BLKS && t < blockIdx.x) ? bsum[t] : 0;
  __syncthreads();
  for (int d = 128; d; d >>= 1) {
    if (t < d) s[t] += s[t + d];
    __syncthreads();
  }
  int base = s[0];
  int i = blockIdx.x * 256 + t;
  if (i < N_NODES) {
    int o = offs[i] + base;
    offs[i] = o;
    fill[i] = o;
  }
}

__global__ void k_scatter(const int* __restrict__ dst, const int* __restrict__ srcv,
                          const int* __restrict__ ety, const float* __restrict__ norm,
                          int* __restrict__ fill, uint2* __restrict__ erec) {
  int e = blockIdx.x * 256 + threadIdx.x;
  int pos = atomicAdd(&fill[dst[e]], 1);
  erec[pos] = make_uint2((unsigned)srcv[e] | ((unsigned)ety[e] << 16),
                         __float_as_uint(norm[e]));
}

// -------- W -> MFMA-fragment order: Wf[F*64 + lane] (16B), F = kt*16 + nf ---
__global__ void k_prepwf(const float* __restrict__ weight, const float* __restrict__ loop_w,
                         __bf16* __restrict__ Wf) {
  int tid = blockIdx.x * 256 + threadIdx.x;   // grid 288 -> 73728
  int lane6 = tid & 63;
  int F = tid >> 6;
  int kt2 = F >> 4;
  int nf = F & 15;
  int o = nf * 16 + (lane6 & 15);
  int rbase = kt2 * 32 + (lane6 >> 4) * 8;
  bf16x8 v;
#pragma unroll
  for (int j = 0; j < 8; ++j) {
    int r = rbase + j;
    float f = (r < 2048) ? weight[(size_t)r * 256 + o]
                         : loop_w[(size_t)(r - 2048) * 256 + o];
    v[j] = (__bf16)f;
  }
  *(bf16x8*)(Wf + (size_t)tid * 8) = v;
}

// ---- per-edge FMA body (round-11 proven): et -> SGPR, coef via s_load ------
#define AGGE(R, XV, ACC)                                                      \
  do {                                                                        \
    int et_ = __builtin_amdgcn_readfirstlane((int)((R).x >> 16));             \
    float nm_ = __uint_as_float((R).y);                                       \
    f32x2 v0_ = {__uint_as_float((XV).x << 16) * nm_,                         \
                 __uint_as_float((XV).x & 0xffff0000u) * nm_};                 \
    f32x2 v1_ = {__uint_as_float((XV).y << 16) * nm_,                         \
                 __uint_as_float((XV).y & 0xffff0000u) * nm_};                 \
    f32x4 cl_ = *(const f32x4*)(w_comp + et_ * 8);                            \
    f32x4 ch_ = *(const f32x4*)(w_comp + et_ * 8 + 4);                        \
    _Pragma("unroll") for (int b = 0; b < 4; ++b) {                           \
      ACC[b][0] += v0_ * cl_[b];                                              \
      ACC[b][1] += v1_ * cl_[b];                                              \
      ACC[b + 4][0] += v0_ * ch_[b];                                          \
      ACC[b + 4][1] += v1_ * ch_[b];                                          \
    }                                                                         \
  } while (0)

#define EDGE4(RP, I, ACC)                                                     \
  do {                                                                        \
    uint2 r0_ = (RP)[(I) + 0], r1_ = (RP)[(I) + 1];                           \
    uint2 r2_ = (RP)[(I) + 2], r3_ = (RP)[(I) + 3];                           \
    uint2 x0_ = *(const uint2*)(xb + (size_t)(r0_.x & 0xffffu) * IN_FEAT + lo4);\
    uint2 x1_ = *(const uint2*)(xb + (size_t)(r1_.x & 0xffffu) * IN_FEAT + lo4);\
    uint2 x2_ = *(const uint2*)(xb + (size_t)(r2_.x & 0xffffu) * IN_FEAT + lo4);\
    uint2 x3_ = *(const uint2*)(xb + (size_t)(r3_.x & 0xffffu) * IN_FEAT + lo4);\
    AGGE(r0_, x0_, ACC); AGGE(r1_, x1_, ACC);                                 \
    AGGE(r2_, x2_, ACC); AGGE(r3_, x3_, ACC);                                 \
  } while (0)

#define EDGE1(RP, I, ACC)                                                     \
  do {                                                                        \
    uint2 r_ = (RP)[(I)];                                                     \
    uint2 x_ = *(const uint2*)(xb + (size_t)(r_.x & 0xffffu) * IN_FEAT + lo4);\
    AGGE(r_, x_, ACC);                                                        \
  } while (0)

// write one node's 2048 agg values + 256 self-loop values into padded LDS row.
// chunk c of row R at R*ROWB + c*16; lane pair (2i,2i+1) owns chunk b*32+i.
// ROWB = 289 chunks (odd) -> rows not bank-aligned; writes are contiguous 512B.
#define WRITE_ROW(ACC, R, NODE)                                               \
  do {                                                                        \
    char* rowp_ = sA + (size_t)(R) * ROWB;                                    \
    _Pragma("unroll") for (int b = 0; b < 8; ++b) {                           \
      int cp_ = b * 32 + (lane >> 1);                                         \
      bf16x4 o_;                                                              \
      o_[0] = (__bf16)ACC[b][0][0]; o_[1] = (__bf16)ACC[b][0][1];             \
      o_[2] = (__bf16)ACC[b][1][0]; o_[3] = (__bf16)ACC[b][1][1];             \
      *(bf16x4*)(rowp_ + cp_ * 16 + (lane & 1) * 8) = o_;                     \
    }                                                                         \
    uint2 xv_ = ((NODE) < N_NODES)                                            \
        ? *(const uint2*)(xb + (size_t)(NODE) * IN_FEAT + lo4)                \
        : make_uint2(0u, 0u);                                                 \
    int cx_ = 256 + (lane >> 1);                                              \
    *(uint2*)(rowp_ + cx_ * 16 + (lane & 1) * 8) = xv_;                       \
  } while (0)

// dual-chain aggregation of two nodes (round-11 loop), result -> LDS
#define AGG_PAIR(NA, NB, RA, RB)                                              \
  do {                                                                        \
    f32x2 acca[8][2], accb[8][2];                                             \
    _Pragma("unroll") for (int b = 0; b < 8; ++b) {                           \
      acca[b][0] = f32x2{0.f, 0.f}; acca[b][1] = f32x2{0.f, 0.f};             \
      accb[b][0] = f32x2{0.f, 0.f}; accb[b][1] = f32x2{0.f, 0.f};             \
    }                                                                         \
    int i0a = 0, ca = 0, i0b = 0, cb = 0;                                     \
    if ((NA) < N_NODES) {                                                     \
      i0a = __builtin_amdgcn_readfirstlane(offs[NA]);                         \
      ca  = __builtin_amdgcn_readfirstlane(fin[NA]) - i0a;                    \
    }                                                                         \
    if ((NB) < N_NODES) {                                                     \
      i0b = __builtin_amdgcn_readfirstlane(offs[NB]);                         \
      cb  = __builtin_amdgcn_readfirstlane(fin[NB]) - i0b;                    \
    }                                                                         \
    const uint2* rpa = erec + i0a;                                            \
    const uint2* rpb = erec + i0b;                                            \
    int ia = 0, ib = 0;                                                       \
    int mm = (ca < cb ? ca : cb) & ~3;                                        \
    for (; ia < mm; ia += 4, ib += 4) {                                       \
      EDGE4(rpa, ia, acca);                                                   \
      EDGE4(rpb, ib, accb);                                                   \
    }                                                                         \
    for (; ia + 4 <= ca; ia += 4) EDGE4(rpa, ia, acca);                       \
    for (; ib + 4 <= cb; ib += 4) EDGE4(rpb, ib, accb);                       \
    for (; ia < ca; ++ia) EDGE1(rpa, ia, acca);                               \
    for (; ib < cb; ++ib) EDGE1(rpb, ib, accb);                               \
    WRITE_ROW(acca, RA, NA);                                                  \
    WRITE_ROW(accb, RB, NB);                                                  \
  } while (0)

// ---------------- FUSED: aggregate 32 nodes -> LDS -> GEMM -> out -----------
// 1024 threads = 16 waves (2x round-13's latency hiding). Phase 1: wave w
// aggregates nodes {tm*32+2w, +1} (dual-chain) into padded LDS rows 2w,2w+1.
// ONE barrier. Phase 2: wave w computes cols [w*16, w*16+16): acc[2] m-frags,
// A via ds_read_b128 from the padded tile (2-way bank aliasing = free),
// B from frag-packed Wf (L2-resident), both double-buffered in registers.
__global__ __launch_bounds__(1024, 4) void k_fused(
    const __bf16* __restrict__ xb, const float* __restrict__ w_comp,
    const int* __restrict__ offs, const int* __restrict__ fin,
    const uint2* __restrict__ erec, const __bf16* __restrict__ Wf,
    const float* __restrict__ bias, float* __restrict__ out) {
  __shared__ __align__(16) char sA[32 * ROWB];   // 144.5KB

  int t = threadIdx.x;
  int wid = t >> 6, lane = t & 63;
  int tm = blockIdx.x;
  int lo4 = lane * 4;

  {
    int na = tm * 32 + wid * 2;
    AGG_PAIR(na, na + 1, wid * 2, wid * 2 + 1);
  }
  __syncthreads();

  // ---- phase 2: [32][2304] @ Wcat, barrier-free ----
  int frow = lane & 15, g = lane >> 4;
  const char* ap0 = (const char*)sA + (size_t)frow * ROWB + g * 16;
  const char* ap1 = (const char*)sA + (size_t)(16 + frow) * ROWB + g * 16;

  f32x4 acc2[2];
  acc2[0] = f32x4{0.f, 0.f, 0.f, 0.f};
  acc2[1] = f32x4{0.f, 0.f, 0.f, 0.f};

  bf16x8 Aa[2], Ab[2], B0, B1;

#define LD_A(KT, D)                                                           \
  do {                                                                        \
    D[0] = *(const bf16x8*)(ap0 + (KT) * 64);                                 \
    D[1] = *(const bf16x8*)(ap1 + (KT) * 64);                                 \
  } while (0)

#define LD_B(KT, D)                                                           \
  do {                                                                        \
    D = *(const bf16x8*)(Wf + (size_t)((KT) * 16 + wid) * 512 + lane * 8);    \
  } while (0)

#define FMA2(AS, BS)                                                          \
  do {                                                                        \
    acc2[0] = __builtin_amdgcn_mfma_f32_16x16x32_bf16(AS[0], BS, acc2[0], 0, 0, 0); \
    acc2[1] = __builtin_amdgcn_mfma_f32_16x16x32_bf16(AS[1], BS, acc2[1], 0, 0, 0); \
  } while (0)

  LD_A(0, Aa); LD_B(0, B0);
  for (int kt = 0; kt < 72; kt += 2) {
    int n1 = kt + 1;
    int n2 = (kt + 2 < 72) ? kt + 2 : 71;
    LD_A(n1, Ab); LD_B(n1, B1); FMA2(Aa, B0);
    LD_A(n2, Aa); LD_B(n2, B0); FMA2(Ab, B1);
  }
#undef LD_A
#undef LD_B
#undef FMA2

  // epilogue: C/D layout col = lane&15, row = (lane>>4)*4 + j
  int r0 = (lane >> 4) * 4;
  int c0 = lane & 15;
  int col = wid * 16 + c0;
  float bv = bias[col];
#pragma unroll
  for (int mf = 0; mf < 2; ++mf) {
    int rowb = tm * 32 + mf * 16 + r0;
#pragma unroll
    for (int j = 0; j < 4; ++j) {
      int row = rowb + j;
      if (row < N_NODES) {
        float v = acc2[mf][j] + bv;
        out[(size_t)row * OUT_FEAT + col] = v > 0.f ? v : 0.f;
      }
    }
  }
}

extern "C" void kernel_launch(void* const* d_in, const int* in_sizes, int n_in,
                              void* d_out, int out_size, void* d_ws, size_t ws_size,
                              hipStream_t stream) {
  const float* x      = (const float*)d_in[0];
  const int*   src    = (const int*)d_in[1];
  const int*   dst    = (const int*)d_in[2];
  const int*   ety    = (const int*)d_in[3];
  const float* norm   = (const float*)d_in[4];
  const float* weight = (const float*)d_in[5];
  const float* w_comp = (const float*)d_in[6];
  const float* h_bias = (const float*)d_in[7];
  const float* loop_w = (const float*)d_in[8];
  float* out = (float*)d_out;

  char* ws = (char*)d_ws;
  __bf16* xb = (__bf16*)ws;                                 // 25.7MB
  size_t off = (size_t)MP * IN_FEAT * 2;
  __bf16* Wf = (__bf16*)(ws + off);                         // 1.18MB (frag-packed W)
  off += (size_t)256 * KTOT * 2;
  uint2* erec = (uint2*)(ws + off);                         // 6.4MB
  off += (size_t)N_EDGES * 8;
  int* deg   = (int*)(ws + off);
  int* offs  = deg + N_NODES;
  int* fill  = offs + N_NODES;
  int* bsum  = fill + N_NODES;

  hipMemsetAsync(deg, 0, N_NODES * sizeof(int), stream);
  k_prex<<<(N_NODES * IN_FEAT / 8) / 256, 256, 0, stream>>>(x, xb);
  k_count<<<N_EDGES / 256, 256, 0, stream>>>(dst, deg);
  k_scan1<<<SCAN_BLKS, 256, 0, stream>>>(deg, offs, bsum);
  k_scan3<<<SCAN_BLKS, 256, 0, stream>>>(offs, bsum, fill);
  k_scatter<<<N_EDGES / 256, 256, 0, stream>>>(dst, src, ety, norm, fill, erec);
  k_prepwf<<<288, 256, 0, stream>>>(weight, loop_w, Wf);
  k_fused<<<MP / 32, 1024, 0, stream>>>(xb, w_comp, offs, fill, erec, Wf, h_bias, out);
}

// Round 15
// 281.023 us; speedup vs baseline: 1.3870x; 1.0598x over previous
//
#include <hip/hip_runtime.h>
#include <hip/hip_bf16.h>
#include <stdint.h>

#define N_NODES 50000
#define N_EDGES 800000
#define IN_FEAT 256
#define OUT_FEAT 256
#define NUM_RELS 64
#define NUM_BASES 8
#define KTOT 2304           // logical K: 8*256 (bases) + 256 (self loop)
#define MP 50176            // 1568 * 32 padded M
#define SCAN_BLKS 196

typedef __attribute__((ext_vector_type(8))) __bf16 bf16x8;
typedef __attribute__((ext_vector_type(4))) __bf16 bf16x4;
typedef __attribute__((ext_vector_type(4))) float f32x4;
typedef __attribute__((ext_vector_type(2))) float f32x2;

// ---------------- fused prep: x->bf16, degree count, W frag-pack ------------
__global__ void k_prep(const float* __restrict__ x, __bf16* __restrict__ xb,
                       const int* __restrict__ dst, int* __restrict__ deg,
                       const float* __restrict__ weight, const float* __restrict__ loop_w,
                       __bf16* __restrict__ Wf) {
  int i = blockIdx.x * 256 + threadIdx.x;      // grid 6250 -> 1.6M
  // x -> bf16 (8 elems/thread)
  const float4* xp = (const float4*)x;
  float4 u = xp[i * 2], v = xp[i * 2 + 1];
  bf16x8 o;
  o[0] = (__bf16)u.x; o[1] = (__bf16)u.y; o[2] = (__bf16)u.z; o[3] = (__bf16)u.w;
  o[4] = (__bf16)v.x; o[5] = (__bf16)v.y; o[6] = (__bf16)v.z; o[7] = (__bf16)v.w;
  *(bf16x8*)(xb + (size_t)i * 8) = o;
  // degree count
  if (i < N_EDGES) atomicAdd(&deg[dst[i]], 1);
  // W -> MFMA-fragment order: Wf[F*64 + lane] (16B), F = kt2*16 + nf
  if (i < 73728) {
    int lane6 = i & 63;
    int F = i >> 6;
    int kt2 = F >> 4;
    int nf = F & 15;
    int oc = nf * 16 + (lane6 & 15);
    int rbase = kt2 * 32 + (lane6 >> 4) * 8;
    bf16x8 w;
#pragma unroll
    for (int j = 0; j < 8; ++j) {
      int r = rbase + j;
      float f = (r < 2048) ? weight[(size_t)r * 256 + oc]
                           : loop_w[(size_t)(r - 2048) * 256 + oc];
      w[j] = (__bf16)f;
    }
    *(bf16x8*)(Wf + (size_t)i * 8) = w;
  }
}

// ---------------- CSR build ----------------
__global__ void k_scan1(const int* __restrict__ deg, int* __restrict__ offs,
                        int* __restrict__ bsum) {
  __shared__ int s[256];
  int t = threadIdx.x;
  int i = blockIdx.x * 256 + t;
  int v = (i < N_NODES) ? deg[i] : 0;
  s[t] = v;
  __syncthreads();
  for (int d = 1; d < 256; d <<= 1) {
    int y = (t >= d) ? s[t - d] : 0;
    __syncthreads();
    s[t] += y;
    __syncthreads();
  }
  if (i < N_NODES) offs[i] = s[t] - v;
  if (t == 255) bsum[blockIdx.x] = s[255];
}

__global__ void k_scan3(int* __restrict__ offs, const int* __restrict__ bsum,
                        int* __restrict__ fill) {
  __shared__ int s[256];
  int t = threadIdx.x;
  s[t] = (t < SCAN_BLKS && t < blockIdx.x) ? bsum[t] : 0;
  __syncthreads();
  for (int d = 128; d; d >>= 1) {
    if (t < d) s[t] += s[t + d];
    __syncthreads();
  }
  int base = s[0];
  int i = blockIdx.x * 256 + t;
  if (i < N_NODES) {
    int o = offs[i] + base;
    offs[i] = o;
    fill[i] = o;
  }
}

__global__ void k_scatter(const int* __restrict__ dst, const int* __restrict__ srcv,
                          const int* __restrict__ ety, const float* __restrict__ norm,
                          int* __restrict__ fill, uint2* __restrict__ erec) {
  int e = blockIdx.x * 256 + threadIdx.x;
  int pos = atomicAdd(&fill[dst[e]], 1);
  erec[pos] = make_uint2((unsigned)srcv[e] | ((unsigned)ety[e] << 16),
                         __float_as_uint(norm[e]));
}

// ---- per-edge FMA body (round-11 proven): et -> SGPR, coef via s_load ------
#define AGGE(R, XV, ACC)                                                      \
  do {                                                                        \
    int et_ = __builtin_amdgcn_readfirstlane((int)((R).x >> 16));             \
    float nm_ = __uint_as_float((R).y);                                       \
    f32x2 v0_ = {__uint_as_float((XV).x << 16) * nm_,                         \
                 __uint_as_float((XV).x & 0xffff0000u) * nm_};                 \
    f32x2 v1_ = {__uint_as_float((XV).y << 16) * nm_,                         \
                 __uint_as_float((XV).y & 0xffff0000u) * nm_};                 \
    f32x4 cl_ = *(const f32x4*)(w_comp + et_ * 8);                            \
    f32x4 ch_ = *(const f32x4*)(w_comp + et_ * 8 + 4);                        \
    _Pragma("unroll") for (int b = 0; b < 4; ++b) {                           \
      ACC[b][0] += v0_ * cl_[b];                                              \
      ACC[b][1] += v1_ * cl_[b];                                              \
      ACC[b + 4][0] += v0_ * ch_[b];                                          \
      ACC[b + 4][1] += v1_ * ch_[b];                                          \
    }                                                                         \
  } while (0)

#define EDGE4(RP, I, ACC)                                                     \
  do {                                                                        \
    uint2 r0_ = (RP)[(I) + 0], r1_ = (RP)[(I) + 1];                           \
    uint2 r2_ = (RP)[(I) + 2], r3_ = (RP)[(I) + 3];                           \
    uint2 x0_ = *(const uint2*)(xb + (size_t)(r0_.x & 0xffffu) * IN_FEAT + lo4);\
    uint2 x1_ = *(const uint2*)(xb + (size_t)(r1_.x & 0xffffu) * IN_FEAT + lo4);\
    uint2 x2_ = *(const uint2*)(xb + (size_t)(r2_.x & 0xffffu) * IN_FEAT + lo4);\
    uint2 x3_ = *(const uint2*)(xb + (size_t)(r3_.x & 0xffffu) * IN_FEAT + lo4);\
    AGGE(r0_, x0_, ACC); AGGE(r1_, x1_, ACC);                                 \
    AGGE(r2_, x2_, ACC); AGGE(r3_, x3_, ACC);                                 \
  } while (0)

#define EDGE1(RP, I, ACC)                                                     \
  do {                                                                        \
    uint2 r_ = (RP)[(I)];                                                     \
    uint2 x_ = *(const uint2*)(xb + (size_t)(r_.x & 0xffffu) * IN_FEAT + lo4);\
    AGGE(r_, x_, ACC);                                                        \
  } while (0)

// write node-row R into kt-tiled LDS: A-tile = [kt][32 rows][128B], 4KB/kt.
// logical 16B-chunk c8 of (row, kt) at kt*4096 + R*128 + (c8 ^ (R&7))*16.
// For basis b, lane l: k = b*256 + l*4 + j -> kt = b*4 + (l>>4),
// c8 = (l>>1)&7, byte-in-chunk = (l&1)*8.  Self-loop x -> kt 32 + (l>>4).
#define WRITE_ROW(ACC, R, NODE)                                               \
  do {                                                                        \
    char* base_ = sA + (size_t)(R) * 128 +                                    \
                  ((((lane >> 1) & 7) ^ ((R) & 7)) * 16 + (lane & 1) * 8);    \
    int ktl_ = lane >> 4;                                                     \
    _Pragma("unroll") for (int b = 0; b < 8; ++b) {                           \
      bf16x4 o_;                                                              \
      o_[0] = (__bf16)ACC[b][0][0]; o_[1] = (__bf16)ACC[b][0][1];             \
      o_[2] = (__bf16)ACC[b][1][0]; o_[3] = (__bf16)ACC[b][1][1];             \
      *(bf16x4*)(base_ + (b * 4 + ktl_) * 4096) = o_;                         \
    }                                                                         \
    uint2 xv_ = ((NODE) < N_NODES)                                            \
        ? *(const uint2*)(xb + (size_t)(NODE) * IN_FEAT + lo4)                \
        : make_uint2(0u, 0u);                                                 \
    *(uint2*)(base_ + (32 + ktl_) * 4096) = xv_;                              \
  } while (0)

// dual-chain aggregation of two nodes (round-11 loop), result -> LDS
#define AGG_PAIR(NA, NB, RA, RB)                                              \
  do {                                                                        \
    f32x2 acca[8][2], accb[8][2];                                             \
    _Pragma("unroll") for (int b = 0; b < 8; ++b) {                           \
      acca[b][0] = f32x2{0.f, 0.f}; acca[b][1] = f32x2{0.f, 0.f};             \
      accb[b][0] = f32x2{0.f, 0.f}; accb[b][1] = f32x2{0.f, 0.f};             \
    }                                                                         \
    int i0a = 0, ca = 0, i0b = 0, cb = 0;                                     \
    if ((NA) < N_NODES) {                                                     \
      i0a = __builtin_amdgcn_readfirstlane(offs[NA]);                         \
      ca  = __builtin_amdgcn_readfirstlane(fin[NA]) - i0a;                    \
    }                                                                         \
    if ((NB) < N_NODES) {                                                     \
      i0b = __builtin_amdgcn_readfirstlane(offs[NB]);                         \
      cb  = __builtin_amdgcn_readfirstlane(fin[NB]) - i0b;                    \
    }                                                                         \
    const uint2* rpa = erec + i0a;                                            \
    const uint2* rpb = erec + i0b;                                            \
    int ia = 0, ib = 0;                                                       \
    int mm = (ca < cb ? ca : cb) & ~3;                                        \
    for (; ia < mm; ia += 4, ib += 4) {                                       \
      EDGE4(rpa, ia, acca);                                                   \
      EDGE4(rpb, ib, accb);                                                   \
    }                                                                         \
    for (; ia + 4 <= ca; ia += 4) EDGE4(rpa, ia, acca);                       \
    for (; ib + 4 <= cb; ib += 4) EDGE4(rpb, ib, accb);                       \
    for (; ia < ca; ++ia) EDGE1(rpa, ia, acca);                               \
    for (; ib < cb; ++ib) EDGE1(rpb, ib, accb);                               \
    WRITE_ROW(acca, RA, NA);                                                  \
    WRITE_ROW(accb, RB, NB);                                                  \
  } while (0)

// ---------------- FUSED: aggregate 32 nodes -> LDS -> GEMM -> out -----------
// 16 waves. Phase 1: wave w aggregates nodes {tm*32+2w, +1} into kt-tiled LDS.
// ONE barrier. Phase 2: wave w computes cols [w*16, +16): A via ds_read_b128
// from the 128B-row swizzled tiles (rounds-4-11 proven zero-conflict pattern),
// B from frag-packed Wf (L2), both double-buffered in registers; barrier-free.
__global__ __launch_bounds__(1024, 4) void k_fused(
    const __bf16* __restrict__ xb, const float* __restrict__ w_comp,
    const int* __restrict__ offs, const int* __restrict__ fin,
    const uint2* __restrict__ erec, const __bf16* __restrict__ Wf,
    const float* __restrict__ bias, float* __restrict__ out) {
  __shared__ __align__(16) char sA[36 * 4096];   // 144KB: kt 0..31 bases, 32..35 x

  int t = threadIdx.x;
  int wid = t >> 6, lane = t & 63;
  int tm = blockIdx.x;
  int lo4 = lane * 4;

  {
    int na = tm * 32 + wid * 2;
    AGG_PAIR(na, na + 1, wid * 2, wid * 2 + 1);
  }
  __syncthreads();

  // ---- phase 2: [32][2304] @ Wcat, barrier-free ----
  int frow = lane & 15, g = lane >> 4;
  int kb0 = ((g ^ (frow & 7)) << 4);
  int kb1 = (((4 + g) ^ (frow & 7)) << 4);
  const char* ap0 = (const char*)sA + frow * 128;
  const char* ap1 = (const char*)sA + (16 + frow) * 128;

  f32x4 acc2[2];
  acc2[0] = f32x4{0.f, 0.f, 0.f, 0.f};
  acc2[1] = f32x4{0.f, 0.f, 0.f, 0.f};

  bf16x8 Aa[2], Ab[2], B0, B1;

  // K2 = 0..71 indexes K=32 slices; kt = K2>>1 (4KB tile), half = K2&1.
#define LD_A(K2, HALF, D)                                                     \
  do {                                                                        \
    int off_ = ((K2) >> 1) * 4096 + ((HALF) ? kb1 : kb0);                     \
    D[0] = *(const bf16x8*)(ap0 + off_);                                      \
    D[1] = *(const bf16x8*)(ap1 + off_);                                      \
  } while (0)

#define LD_B(K2, D)                                                           \
  do {                                                                        \
    D = *(const bf16x8*)(Wf + (size_t)((K2) * 16 + wid) * 512 + lane * 8);    \
  } while (0)

#define FMA2(AS, BS)                                                          \
  do {                                                                        \
    acc2[0] = __builtin_amdgcn_mfma_f32_16x16x32_bf16(AS[0], BS, acc2[0], 0, 0, 0); \
    acc2[1] = __builtin_amdgcn_mfma_f32_16x16x32_bf16(AS[1], BS, acc2[1], 0, 0, 0); \
  } while (0)

  LD_A(0, 0, Aa); LD_B(0, B0);
  for (int kt = 0; kt < 72; kt += 2) {
    int n1 = kt + 1;
    int n2 = (kt + 2 < 72) ? kt + 2 : 70;
    LD_A(n1, 1, Ab); LD_B(n1, B1); FMA2(Aa, B0);
    LD_A(n2, 0, Aa); LD_B(n2, B0); FMA2(Ab, B1);
  }
#undef LD_A
#undef LD_B
#undef FMA2

  // epilogue: C/D layout col = lane&15, row = (lane>>4)*4 + j
  int r0 = (lane >> 4) * 4;
  int c0 = lane & 15;
  int col = wid * 16 + c0;
  float bv = bias[col];
#pragma unroll
  for (int mf = 0; mf < 2; ++mf) {
    int rowb = tm * 32 + mf * 16 + r0;
#pragma unroll
    for (int j = 0; j < 4; ++j) {
      int row = rowb + j;
      if (row < N_NODES) {
        float v = acc2[mf][j] + bv;
        out[(size_t)row * OUT_FEAT + col] = v > 0.f ? v : 0.f;
      }
    }
  }
}

extern "C" void kernel_launch(void* const* d_in, const int* in_sizes, int n_in,
                              void* d_out, int out_size, void* d_ws, size_t ws_size,
                              hipStream_t stream) {
  const float* x      = (const float*)d_in[0];
  const int*   src    = (const int*)d_in[1];
  const int*   dst    = (const int*)d_in[2];
  const int*   ety    = (const int*)d_in[3];
  const float* norm   = (const float*)d_in[4];
  const float* weight = (const float*)d_in[5];
  const float* w_comp = (const float*)d_in[6];
  const float* h_bias = (const float*)d_in[7];
  const float* loop_w = (const float*)d_in[8];
  float* out = (float*)d_out;

  char* ws = (char*)d_ws;
  __bf16* xb = (__bf16*)ws;                                 // 25.7MB
  size_t off = (size_t)MP * IN_FEAT * 2;
  __bf16* Wf = (__bf16*)(ws + off);                         // 1.18MB (frag-packed W)
  off += (size_t)256 * KTOT * 2;
  uint2* erec = (uint2*)(ws + off);                         // 6.4MB
  off += (size_t)N_EDGES * 8;
  int* deg   = (int*)(ws + off);
  int* offs  = deg + N_NODES;
  int* fill  = offs + N_NODES;
  int* bsum  = fill + N_NODES;

  hipMemsetAsync(deg, 0, N_NODES * sizeof(int), stream);
  k_prep<<<(N_NODES * IN_FEAT / 8) / 256, 256, 0, stream>>>(x, xb, dst, deg,
                                                            weight, loop_w, Wf);
  k_scan1<<<SCAN_BLKS, 256, 0, stream>>>(deg, offs, bsum);
  k_scan3<<<SCAN_BLKS, 256, 0, stream>>>(offs, bsum, fill);
  k_scatter<<<N_EDGES / 256, 256, 0, stream>>>(dst, src, ety, norm, fill, erec);
  k_fused<<<MP / 32, 1024, 0, stream>>>(xb, w_comp, offs, fill, erec, Wf, h_bias, out);
}